// Round 9
// baseline (197.611 us; speedup 1.0000x reference)
//
#include <hip/hip_runtime.h>
#include <math.h>

#define BB 8
#define DD 256
#define NN 2048
#define NH 4
#define DH 64

typedef _Float16 half8   __attribute__((ext_vector_type(8)));
typedef _Float16 half4_t __attribute__((ext_vector_type(4)));
typedef _Float16 half2_t __attribute__((ext_vector_type(2)));
typedef float    floatx4 __attribute__((ext_vector_type(4)));
typedef unsigned int uint32x4 __attribute__((ext_vector_type(4)));

#define MFMA32(A, B, C) __builtin_amdgcn_mfma_f32_16x16x32_f16(A, B, C, 0, 0, 0)

// softmax scale folded into Q: 0.125 * log2(e)
#define SC 0.18033688011112042f

// ---------------------------------------------------------------------------
// Fused Q/K/V projections, weights converted f32->f16 IN-KERNEL (prep_weights
// kernel eliminated; weights are 1MB, L2/L3-resident — redundant per-block
// conversion is cheap). grid (32, 8, 3): z = tensor. X tile staged ONCE per
// block (f16 LDS [n 64][k 264-pitch], 16B-slot XOR swizzle), both cout halves
// in-block. Weight frag loads chunked (8 float4 live) to stay under the
// 128-VGPR cap of __launch_bounds__(256,3).
// Q,K out: f16 Y[(b*4+h)*2048+n][d]  (cout = 4d+h; Q scaled by SC)
// V   out: f16 Y[((b*4+h)*64+d)][n]
// ---------------------------------------------------------------------------
__global__ __launch_bounds__(256, 3) void conv_qkv(
    const float* __restrict__ wq, const float* __restrict__ wk,
    const float* __restrict__ wv,
    const float* __restrict__ bq, const float* __restrict__ bk,
    const float* __restrict__ bv,
    const float* __restrict__ Xq, const float* __restrict__ Xk,
    const float* __restrict__ Xv,
    _Float16* __restrict__ Yq, _Float16* __restrict__ Yk,
    _Float16* __restrict__ Yv)
{
    const int n0 = blockIdx.x * 64;
    const int b  = blockIdx.y;
    const int z  = blockIdx.z;      // tensor
    const float* W32  = z == 0 ? wq : (z == 1 ? wk : wv);
    const float* bias = z == 0 ? bq : (z == 1 ? bk : bv);
    const float* X    = z == 0 ? Xq : (z == 1 ? Xk : Xv);
    const float osc   = z == 0 ? SC : 1.0f;

    const int t = threadIdx.x;
    const int w = t >> 6, l = t & 63, c = l & 15, q = l >> 4;

    __shared__ _Float16 smem[64 * 264 + 9216];   // Xs + Es = 52.2 KB
    _Float16* Xs = smem;
    _Float16* Es = smem + 64 * 264;

    const int gk = (c & 3) << 1;   // read-swizzle group (row ≡ c mod 4)

    // stage X fp32 [k][n] -> Xs f16 [n][k] pitch 264, swizzled 16B slots
    {
        const int nb = t & 15, kb = t >> 4;
        const int slot = (kb >> 1), sub = (kb & 1) * 4;
        #pragma unroll
        for (int cc = 0; cc < 4; ++cc) {
            const float* Xg = X + (size_t)b * DD * NN +
                              (size_t)(cc * 64 + kb * 4) * NN + n0 + nb * 4;
            float4 x[4];
            #pragma unroll
            for (int i = 0; i < 4; ++i) x[i] = *(const float4*)(Xg + (size_t)i * NN);
            #pragma unroll
            for (int j = 0; j < 4; ++j) {
                half4_t hv;
                #pragma unroll
                for (int i = 0; i < 4; ++i) hv[i] = (_Float16)(((const float*)&x[i])[j]);
                *(half4_t*)(Xs + (nb * 4 + j) * 264 +
                            (((cc * 8 + slot) ^ (j << 1)) << 3) + sub) = hv;
            }
        }
    }
    __syncthreads();

    for (int hf = 0; hf < 2; ++hf) {
        const int cout0 = hf * 128;

        // A-frags: lane reads its 32B f32 row-slice, converts to f16.
        // Chunked 4-ch groups: 8 float4 (32 VGPR) live at a time.
        half8 af[2][8];
        {
            const float* wp = W32 + (size_t)(cout0 + w * 32 + c) * 256 + q * 8;
            #pragma unroll
            for (int rt = 0; rt < 2; ++rt)
                #pragma unroll
                for (int cg = 0; cg < 2; ++cg) {
                    float4 tmp[8];
                    #pragma unroll
                    for (int u = 0; u < 4; ++u) {
                        const float* p = wp + rt * 16 * 256 + (cg * 4 + u) * 32;
                        tmp[u * 2]     = *(const float4*)(p);
                        tmp[u * 2 + 1] = *(const float4*)(p + 4);
                    }
                    #pragma unroll
                    for (int u = 0; u < 4; ++u) {
                        half8 hv;
                        #pragma unroll
                        for (int j = 0; j < 4; ++j) {
                            hv[j]     = (_Float16)(((const float*)&tmp[u * 2])[j]);
                            hv[4 + j] = (_Float16)(((const float*)&tmp[u * 2 + 1])[j]);
                        }
                        af[rt][cg * 4 + u] = hv;
                    }
                }
        }

        floatx4 acc[2][4];
        #pragma unroll
        for (int rt = 0; rt < 2; ++rt)
            #pragma unroll
            for (int nt = 0; nt < 4; ++nt) acc[rt][nt] = (floatx4){0.f, 0.f, 0.f, 0.f};

        #pragma unroll
        for (int ch = 0; ch < 8; ++ch)
            #pragma unroll
            for (int nt = 0; nt < 4; ++nt) {
                half8 bx = *(const half8*)(Xs + (nt * 16 + c) * 264 +
                                           (((ch * 4 + q) ^ gk) << 3));
                acc[0][nt] = MFMA32(af[0][ch], bx, acc[0][nt]);
                acc[1][nt] = MFMA32(af[1][ch], bx, acc[1][nt]);
            }

        if (z < 2) {
            // stage [n 64][cl 128] pitch 136, gather 32-d runs per (n, h)
            __syncthreads();
            #pragma unroll
            for (int rt = 0; rt < 2; ++rt)
                #pragma unroll
                for (int nt = 0; nt < 4; ++nt) {
                    half4_t hv;
                    #pragma unroll
                    for (int r = 0; r < 4; ++r)
                        hv[r] = (_Float16)((acc[rt][nt][r] +
                                bias[cout0 + w * 32 + rt * 16 + q * 4 + r]) * osc);
                    *(half4_t*)(Es + (nt * 16 + c) * 136 + w * 32 + rt * 16 + q * 4) = hv;
                }
            __syncthreads();
            _Float16* Y = z == 0 ? Yq : Yk;
            const int nn = t >> 2, hh = t & 3;
            half8 hv[4];
            #pragma unroll
            for (int i = 0; i < 4; ++i)
                #pragma unroll
                for (int k = 0; k < 8; ++k)
                    hv[i][k] = Es[nn * 136 + (i * 8 + k) * 4 + hh];
            _Float16* dst = Y + ((size_t)(b * NH + hh) * NN + n0 + nn) * 64 + hf * 32;
            #pragma unroll
            for (int i = 0; i < 4; ++i) *(half8*)(dst + i * 8) = hv[i];
        } else {
            // stage [cl 128][n 64] pitch 72, row-write per cout
            __syncthreads();
            #pragma unroll
            for (int rt = 0; rt < 2; ++rt)
                #pragma unroll
                for (int nt = 0; nt < 4; ++nt)
                    #pragma unroll
                    for (int r = 0; r < 4; ++r)
                        Es[(w * 32 + rt * 16 + q * 4 + r) * 72 + nt * 16 + c] =
                            (_Float16)(acc[rt][nt][r] +
                                       bias[cout0 + w * 32 + rt * 16 + q * 4 + r]);
            __syncthreads();
            const int cl = t >> 1, noff = (t & 1) * 32;
            const int cout = cout0 + cl;
            const int hh = cout & 3, dd = cout >> 2;
            _Float16* dst = Yv + ((size_t)(b * NH + hh) * 64 + dd) * NN + n0 + noff;
            #pragma unroll
            for (int i = 0; i < 4; ++i)
                *(half8*)(dst + i * 8) = *(const half8*)(Es + cl * 72 + noff + i * 8);
        }
    }
}

// ---------------------------------------------------------------------------
// Final projection: packed weights in regs, B-frags DIRECT from PACKED global
// Atp (contiguous 1KB wave-reads). Output fp32 [b][cout][n].
// grid (32, 8, 2): z = cout half.
// ---------------------------------------------------------------------------
__global__ __launch_bounds__(256, 3) void conv_o(
    const _Float16* __restrict__ Wf, const float* __restrict__ bias,
    const _Float16* __restrict__ At, float* __restrict__ out)
{
    const int n0 = blockIdx.x * 64;
    const int b  = blockIdx.y;
    const int hf = blockIdx.z;
    const int cout0 = hf * 128;

    const int t = threadIdx.x;
    const int w = t >> 6, l = t & 63, c = l & 15, q = l >> 4;

    __shared__ float fs[128 * 66];   // 33.8 KB

    // packed af: cb = hf*8 + w*2 + rt
    half8 af[2][8];
    {
        const _Float16* wp = Wf + (size_t)(hf * 8 + w * 2) * 4096 + l * 8;
        #pragma unroll
        for (int rt = 0; rt < 2; ++rt)
            #pragma unroll
            for (int ch = 0; ch < 8; ++ch)
                af[rt][ch] = *(const half8*)(wp + rt * 4096 + ch * 512);
    }

    floatx4 acc[2][4];
    #pragma unroll
    for (int rt = 0; rt < 2; ++rt)
        #pragma unroll
        for (int nt = 0; nt < 4; ++nt) acc[rt][nt] = (floatx4){0.f, 0.f, 0.f, 0.f};

    #pragma unroll
    for (int ch = 0; ch < 8; ++ch)
        #pragma unroll
        for (int nt = 0; nt < 4; ++nt) {
            half8 bx = *(const half8*)(At +
                ((((size_t)b * 128 + (n0 >> 4) + nt) * 8 + ch) << 9) + l * 8);
            acc[0][nt] = MFMA32(af[0][ch], bx, acc[0][nt]);
            acc[1][nt] = MFMA32(af[1][ch], bx, acc[1][nt]);
        }

    #pragma unroll
    for (int rt = 0; rt < 2; ++rt)
        #pragma unroll
        for (int nt = 0; nt < 4; ++nt)
            #pragma unroll
            for (int r = 0; r < 4; ++r)
                fs[(w * 32 + rt * 16 + q * 4 + r) * 66 + nt * 16 + c] =
                    acc[rt][nt][r] + bias[cout0 + w * 32 + rt * 16 + q * 4 + r];
    __syncthreads();
    const int cl = t >> 1, noff = (t & 1) * 32;
    float* dst = out + (size_t)b * DD * NN + (size_t)(cout0 + cl) * NN + n0 + noff;
    #pragma unroll
    for (int i = 0; i < 8; ++i)
        *(float4*)(dst + i * 4) = *(const float4*)(fs + cl * 66 + noff + i * 4);
}

// ---------------------------------------------------------------------------
// MFMA flash attention v12 = v11 (round-8 best: in-block m-split, 8 waves,
// m-tile 64, K+V dbuf LDS, jj=2, packed p8, lp via ones-MFMA, setprio(1)
// around compute, packed-At epilogue) + wm-prep preamble on the 16 blocks
// with (b==0, h==0): each converts 4096 wm f32 elems into the packed-frag
// f16 layout conv_o consumes (runs concurrent with other blocks' main loops;
// conv_o is stream-ordered after attn). Replaces the prep_weights kernel.
// grid (16, 4, 8) = 512 blocks = 2 blocks/CU.
// ---------------------------------------------------------------------------
__global__ __launch_bounds__(512, 4) void attn_mfma12(
    const _Float16* __restrict__ Qt, const _Float16* __restrict__ Kt,
    const _Float16* __restrict__ V, _Float16* __restrict__ At,
    const float* __restrict__ wm, _Float16* __restrict__ wmf)
{
    const int n0 = blockIdx.x * 128;
    const int h  = blockIdx.y;
    const int b  = blockIdx.z;
    const int t  = threadIdx.x;
    const int w  = t >> 6, l = t & 63, c = l & 15, q = l >> 4;
    const int mh = w >> 2;          // m-half (0: m<1024, 1: m>=1024)
    const int w4 = w & 3;           // wave-in-half -> q-col group
    const int tp = t & 255;         // thread-in-half

    // wm prep: 16 blocks (b==0,h==0) x 512 thr x 8 elems = 65536
    // packed dst base = bx*512 + t; src = wm[cout][(k&63)*4 + (k>>6)],
    // k = ch*32 + qq*8 + j  ->  src = cout*256 + ((ch&1)*32+qq*8+j)*4 + (ch>>1)
    if (b == 0 && h == 0) {
        const int base = blockIdx.x * 512 + t;
        const int cc = base & 15, qq = (base >> 4) & 3;
        const int ch = (base >> 6) & 7, cb = base >> 9;
        const int cout = cb * 16 + cc;
        const float* srcp = wm + cout * 256 + ((ch & 1) * 32 + qq * 8) * 4 + (ch >> 1);
        half8 hv;
        #pragma unroll
        for (int j = 0; j < 8; ++j) hv[j] = (_Float16)srcp[j * 4];
        *(half8*)(wmf + base * 8) = hv;
    }

    const size_t bh = (size_t)(b * NH + h);

    // layout: [mh][buf][Ks 4608 | Vs 4608] = 2*2*9216 = 36864 halfs (73.7 KB)
    __shared__ _Float16 smem[36864];
    _Float16* base_s = smem + mh * 18432;

    // Q frags: wave covers q-cols w4*32 + jj*16 + c
    half8 bq2[2][2];
    #pragma unroll
    for (int jj = 0; jj < 2; ++jj)
        #pragma unroll
        for (int ch = 0; ch < 2; ++ch)
            bq2[jj][ch] = *(const half8*)(Qt +
                (bh * NN + n0 + w4 * 32 + jj * 16 + c) * 64 + ch * 32 + q * 8);

    // all-ones A-frag for the lp row-sum MFMA
    half8 ones;
    #pragma unroll
    for (int i = 0; i < 8; ++i) ones[i] = (_Float16)1.0f;

    floatx4 lpa[2];
    floatx4 o[2][4];
    #pragma unroll
    for (int jj = 0; jj < 2; ++jj) {
        lpa[jj] = (floatx4){0.f, 0.f, 0.f, 0.f};
        #pragma unroll
        for (int dt = 0; dt < 4; ++dt) o[jj][dt] = (floatx4){0.f, 0.f, 0.f, 0.f};
    }

    // staging (256 thr per half): K row 64x64 by 4 thr; V d-row 64x64m by 4 thr
    const int ksr = tp >> 2, ksc = (tp & 3) * 16;
    const int vr  = tp >> 2, vcb = (tp & 3) * 16;
    const _Float16* Kg = Kt + bh * NN * 64 + (size_t)mh * 1024 * 64;  // [m][d]
    const _Float16* Vg = V + bh * 64 * NN + mh * 1024;                // [d][n]

    half8 kpre[2], vpre[2];
    #pragma unroll
    for (int u = 0; u < 2; ++u) {
        kpre[u] = *(const half8*)(Kg + (size_t)ksr * 64 + ksc + u * 8);
        vpre[u] = *(const half8*)(Vg + (size_t)vr * NN + vcb + u * 8);
    }

#define STAGE8(BUFP)                                                            \
    {                                                                           \
        _Float16* Ksp_ = (BUFP);                                                \
        *(half8*)(Ksp_ + ksr * 72 + ksc)     = kpre[0];                         \
        *(half8*)(Ksp_ + ksr * 72 + ksc + 8) = kpre[1];                         \
        _Float16* Vsp_ = (BUFP) + 4608;                                         \
        _Pragma("unroll")                                                       \
        for (int u = 0; u < 2; ++u) {                                           \
            const int mb = vcb + u * 8;                                         \
            const int p0 = (mb & ~31) + (((mb >> 2) & 3) << 3) +                \
                           (((mb >> 4) & 1) << 2);                              \
            half4_t lo, hi;                                                     \
            _Pragma("unroll")                                                   \
            for (int j = 0; j < 4; ++j) { lo[j] = vpre[u][j]; hi[j] = vpre[u][4 + j]; } \
            *(half4_t*)(Vsp_ + vr * 72 + p0)     = lo;                          \
            *(half4_t*)(Vsp_ + vr * 72 + p0 + 8) = hi;                          \
        }                                                                       \
    }

    // prologue: stage tile0 -> buf0, prefetch tile1
    STAGE8(base_s);
    #pragma unroll
    for (int u = 0; u < 2; ++u) {
        kpre[u] = *(const half8*)(Kg + (size_t)(64 + ksr) * 64 + ksc + u * 8);
        vpre[u] = *(const half8*)(Vg + (size_t)vr * NN + 64 + vcb + u * 8);
    }
    __syncthreads();

    for (int it = 0; it < 16; ++it) {
        if (it < 15) STAGE8(base_s + ((it + 1) & 1) * 9216);
        {
            const int mn = (it + 2 < 16) ? (it + 2) * 64 : it * 64;
            #pragma unroll
            for (int u = 0; u < 2; ++u) {
                kpre[u] = *(const half8*)(Kg + (size_t)(mn + ksr) * 64 + ksc + u * 8);
                vpre[u] = *(const half8*)(Vg + (size_t)vr * NN + mn + vcb + u * 8);
            }
        }
        const _Float16* Ks = base_s + (it & 1) * 9216;
        const _Float16* Vs = Ks + 4608;
        __builtin_amdgcn_s_setprio(1);
        #pragma unroll
        for (int mt2 = 0; mt2 < 2; ++mt2) {
            uint32x4 pu[2];
            #pragma unroll
            for (int hfm = 0; hfm < 2; ++hfm) {
                const int mt = mt2 * 2 + hfm;
                half8 ak0 = *(const half8*)(Ks + (mt * 16 + c) * 72 + q * 8);
                half8 ak1 = *(const half8*)(Ks + (mt * 16 + c) * 72 + 32 + q * 8);
                #pragma unroll
                for (int jj = 0; jj < 2; ++jj) {
                    floatx4 s = {0.f, 0.f, 0.f, 0.f};
                    s = MFMA32(ak0, bq2[jj][0], s);
                    s = MFMA32(ak1, bq2[jj][1], s);
                    float e0 = exp2f(s[0]), e1 = exp2f(s[1]);
                    float e2 = exp2f(s[2]), e3 = exp2f(s[3]);
                    pu[jj][hfm * 2 + 0] = __builtin_bit_cast(unsigned int,
                        __builtin_amdgcn_cvt_pkrtz(e0, e1));
                    pu[jj][hfm * 2 + 1] = __builtin_bit_cast(unsigned int,
                        __builtin_amdgcn_cvt_pkrtz(e2, e3));
                }
            }
            const half8 p80 = __builtin_bit_cast(half8, pu[0]);
            const half8 p81 = __builtin_bit_cast(half8, pu[1]);
            lpa[0] = MFMA32(ones, p80, lpa[0]);
            lpa[1] = MFMA32(ones, p81, lpa[1]);
            #pragma unroll
            for (int dt = 0; dt < 4; ++dt) {
                half8 av = *(const half8*)(Vs + (dt * 16 + c) * 72 + mt2 * 32 + q * 8);
                o[0][dt] = MFMA32(av, p80, o[0][dt]);
                o[1][dt] = MFMA32(av, p81, o[1][dt]);
            }
        }
        __builtin_amdgcn_s_setprio(0);
        __syncthreads();
    }
#undef STAGE8

    // lpa[jj][r] identical over r (ones-MFMA rows): lane's q-col sum is lpa[jj][0]

    // merge halves via LDS: fo f32 [col 128][68], lq f32 [col 128],
    // fsm f16 [col 128][72] at disjoint offsets (54 KB total <= 73.7 KB)
    float* fo = (float*)smem;                    // 34816 B
    float* lq = (float*)smem + 128 * 68;         // 512 B
    _Float16* fsm = (_Float16*)(lq + 128);       // 18432 B

    if (mh == 1) {
        #pragma unroll
        for (int jj = 0; jj < 2; ++jj) {
            const int col = w4 * 32 + jj * 16 + c;
            #pragma unroll
            for (int dt = 0; dt < 4; ++dt)
                #pragma unroll
                for (int r = 0; r < 4; ++r)
                    fo[col * 68 + dt * 16 + q * 4 + r] = o[jj][dt][r];
        }
        if (l < 16) {
            lq[w4 * 32 + c]      = lpa[0][0];
            lq[w4 * 32 + 16 + c] = lpa[1][0];
        }
    }
    __syncthreads();
    if (mh == 0) {
        #pragma unroll
        for (int jj = 0; jj < 2; ++jj) {
            const int col = w4 * 32 + jj * 16 + c;
            const float lpt = lpa[jj][0] + lq[col];
            const float inv = 1.f / lpt;
            #pragma unroll
            for (int dt = 0; dt < 4; ++dt) {
                half4_t hv;
                #pragma unroll
                for (int r = 0; r < 4; ++r)
                    hv[r] = (_Float16)((o[jj][dt][r] +
                                        fo[col * 68 + dt * 16 + q * 4 + r]) * inv);
                *(half4_t*)(fsm + col * 72 + dt * 16 + q * 4) = hv;
            }
        }
    }
    __syncthreads();
    if (t < 256) {
        const int seg = (t & 3) * 16;
        const int ch = h * 2 + (seg >> 5);
        const int q0 = (seg >> 3) & 3;
        #pragma unroll
        for (int rr = 0; rr < 2; ++rr) {
            const int rn = rr * 64 + (t >> 2);
            const int n = n0 + rn;
            _Float16* dst = At + ((((size_t)b * 128 + (n >> 4)) * 8 + ch) << 9)
                            + ((n & 15) + 16 * q0) * 8;
            *(half8*)(dst)       = *(const half8*)(fsm + rn * 72 + seg);
            *(half8*)(dst + 128) = *(const half8*)(fsm + rn * 72 + seg + 8);
        }
    }
}

extern "C" void kernel_launch(void* const* d_in, const int* in_sizes, int n_in,
                              void* d_out, int out_size, void* d_ws, size_t ws_size,
                              hipStream_t stream) {
    const float* query = (const float*)d_in[0];
    const float* key_  = (const float*)d_in[1];
    const float* value = (const float*)d_in[2];
    const float* wq    = (const float*)d_in[3];
    const float* bq    = (const float*)d_in[4];
    const float* wk    = (const float*)d_in[5];
    const float* bk    = (const float*)d_in[6];
    const float* wv    = (const float*)d_in[7];
    const float* bv    = (const float*)d_in[8];
    const float* wm    = (const float*)d_in[9];
    const float* bm    = (const float*)d_in[10];
    float* out = (float*)d_out;

    _Float16* ws = (_Float16*)d_ws;
    _Float16* wmf = ws + 196608;                    // packed wm (written by attn)
    const size_t e16 = (size_t)BB * NH * NN * DH;   // 4,194,304
    _Float16* qf = ws + 262144;
    _Float16* kf = qf + e16;
    _Float16* vf = kf + e16;
    _Float16* at = vf + e16;

    conv_qkv<<<dim3(32, 8, 3), 256, 0, stream>>>(wq, wk, wv, bq, bk, bv,
                                                 query, key_, value, qf, kf, vf);
    attn_mfma12<<<dim3(16, 4, 8), 512, 0, stream>>>(qf, kf, vf, at, wm, wmf);
    conv_o<<<dim3(32, 8, 2), 256, 0, stream>>>(wmf, bm, at, out);
}

// Round 10
// 180.705 us; speedup vs baseline: 1.0936x; 1.0936x over previous
//
#include <hip/hip_runtime.h>
#include <math.h>

#define BB 8
#define DD 256
#define NN 2048
#define NH 4
#define DH 64

typedef _Float16 half8   __attribute__((ext_vector_type(8)));
typedef _Float16 half4_t __attribute__((ext_vector_type(4)));
typedef _Float16 half2_t __attribute__((ext_vector_type(2)));
typedef float    floatx4 __attribute__((ext_vector_type(4)));
typedef unsigned int uint32x4 __attribute__((ext_vector_type(4)));

#define MFMA32(A, B, C) __builtin_amdgcn_mfma_f32_16x16x32_f16(A, B, C, 0, 0, 0)

// softmax scale folded into Q: 0.125 * log2(e)
#define SC 0.18033688011112042f

// ---------------------------------------------------------------------------
// Weight prep: cast to f16 and PACK INTO MFMA-FRAGMENT ORDER:
//   wpk[((cb*8 + ch)*64 + c + 16*q)*8 + j] = W[cb*16 + c][ch*32 + q*8 + j]
// so a wave's af load (lane l = c + 16q, 16B) is one contiguous 1KB read.
// wm uses the permuted k-order Wm'[cout][col] = wm[cout][(col&63)*4 + col>>6]
// (attn-out channel order = h*64+d) before packing.
// ---------------------------------------------------------------------------
__global__ __launch_bounds__(256) void prep_weights(
    const float* __restrict__ wq, const float* __restrict__ wk,
    const float* __restrict__ wv, const float* __restrict__ wm,
    _Float16* __restrict__ wqf, _Float16* __restrict__ wkf,
    _Float16* __restrict__ wvf, _Float16* __restrict__ wmf)
{
    int id = blockIdx.x * 256 + threadIdx.x;   // 0..65535 = cout*256 + k
    int cout = id >> 8, k = id & 255;
    int cb = cout >> 4, cc = cout & 15;
    int ch = k >> 5, qq = (k >> 3) & 3, j = k & 7;
    int dst = ((cb * 8 + ch) * 64 + cc + 16 * qq) * 8 + j;
    wqf[dst] = (_Float16)wq[id];
    wkf[dst] = (_Float16)wk[id];
    wvf[dst] = (_Float16)wv[id];
    wmf[dst] = (_Float16)wm[cout * 256 + (k & 63) * 4 + (k >> 6)];
}

// ---------------------------------------------------------------------------
// Fused Q/K/V projections. grid (32, 8, 3): z = tensor. X tile staged ONCE
// per block (f16 LDS [n 64][k 264-pitch], 16B-slot XOR swizzle), then both
// cout halves computed in-block. Weight A-frags from PACKED layout: each
// load is a contiguous 1KB wave-read.
// Q,K out: f16 Y[(b*4+h)*2048+n][d]  (cout = 4d+h; Q scaled by SC)
// V   out: f16 Y[((b*4+h)*64+d)][n]
// ---------------------------------------------------------------------------
__global__ __launch_bounds__(256, 3) void conv_qkv(
    const _Float16* __restrict__ wqf, const _Float16* __restrict__ wkf,
    const _Float16* __restrict__ wvf,
    const float* __restrict__ bq, const float* __restrict__ bk,
    const float* __restrict__ bv,
    const float* __restrict__ Xq, const float* __restrict__ Xk,
    const float* __restrict__ Xv,
    _Float16* __restrict__ Yq, _Float16* __restrict__ Yk,
    _Float16* __restrict__ Yv)
{
    const int n0 = blockIdx.x * 64;
    const int b  = blockIdx.y;
    const int z  = blockIdx.z;      // tensor
    const _Float16* Wf = z == 0 ? wqf : (z == 1 ? wkf : wvf);
    const float* bias  = z == 0 ? bq  : (z == 1 ? bk  : bv);
    const float* X     = z == 0 ? Xq  : (z == 1 ? Xk  : Xv);
    const float osc    = z == 0 ? SC : 1.0f;

    const int t = threadIdx.x;
    const int w = t >> 6, l = t & 63, c = l & 15, q = l >> 4;

    __shared__ _Float16 smem[64 * 264 + 9216];   // Xs + Es = 52.2 KB
    _Float16* Xs = smem;
    _Float16* Es = smem + 64 * 264;

    const int gk = (c & 3) << 1;   // read-swizzle group (row ≡ c mod 4)

    // stage X fp32 [k][n] -> Xs f16 [n][k] pitch 264, swizzled 16B slots
    {
        const int nb = t & 15, kb = t >> 4;
        const int slot = (kb >> 1), sub = (kb & 1) * 4;
        #pragma unroll
        for (int cc = 0; cc < 4; ++cc) {
            const float* Xg = X + (size_t)b * DD * NN +
                              (size_t)(cc * 64 + kb * 4) * NN + n0 + nb * 4;
            float4 x[4];
            #pragma unroll
            for (int i = 0; i < 4; ++i) x[i] = *(const float4*)(Xg + (size_t)i * NN);
            #pragma unroll
            for (int j = 0; j < 4; ++j) {
                half4_t hv;
                #pragma unroll
                for (int i = 0; i < 4; ++i) hv[i] = (_Float16)(((const float*)&x[i])[j]);
                *(half4_t*)(Xs + (nb * 4 + j) * 264 +
                            (((cc * 8 + slot) ^ (j << 1)) << 3) + sub) = hv;
            }
        }
    }
    __syncthreads();

    for (int hf = 0; hf < 2; ++hf) {
        const int cout0 = hf * 128;

        // packed af: cb = hf*8 + w*2 + rt; offset = cb*4096 + ch*512 + l*8
        half8 af[2][8];
        {
            const _Float16* wp = Wf + (size_t)(hf * 8 + w * 2) * 4096 + l * 8;
            #pragma unroll
            for (int rt = 0; rt < 2; ++rt)
                #pragma unroll
                for (int ch = 0; ch < 8; ++ch)
                    af[rt][ch] = *(const half8*)(wp + rt * 4096 + ch * 512);
        }

        floatx4 acc[2][4];
        #pragma unroll
        for (int rt = 0; rt < 2; ++rt)
            #pragma unroll
            for (int nt = 0; nt < 4; ++nt) acc[rt][nt] = (floatx4){0.f, 0.f, 0.f, 0.f};

        #pragma unroll
        for (int ch = 0; ch < 8; ++ch)
            #pragma unroll
            for (int nt = 0; nt < 4; ++nt) {
                half8 bx = *(const half8*)(Xs + (nt * 16 + c) * 264 +
                                           (((ch * 4 + q) ^ gk) << 3));
                acc[0][nt] = MFMA32(af[0][ch], bx, acc[0][nt]);
                acc[1][nt] = MFMA32(af[1][ch], bx, acc[1][nt]);
            }

        if (z < 2) {
            // stage [n 64][cl 128] pitch 136, gather 32-d runs per (n, h)
            __syncthreads();
            #pragma unroll
            for (int rt = 0; rt < 2; ++rt)
                #pragma unroll
                for (int nt = 0; nt < 4; ++nt) {
                    half4_t hv;
                    #pragma unroll
                    for (int r = 0; r < 4; ++r)
                        hv[r] = (_Float16)((acc[rt][nt][r] +
                                bias[cout0 + w * 32 + rt * 16 + q * 4 + r]) * osc);
                    *(half4_t*)(Es + (nt * 16 + c) * 136 + w * 32 + rt * 16 + q * 4) = hv;
                }
            __syncthreads();
            _Float16* Y = z == 0 ? Yq : Yk;
            const int nn = t >> 2, hh = t & 3;
            half8 hv[4];
            #pragma unroll
            for (int i = 0; i < 4; ++i)
                #pragma unroll
                for (int k = 0; k < 8; ++k)
                    hv[i][k] = Es[nn * 136 + (i * 8 + k) * 4 + hh];
            _Float16* dst = Y + ((size_t)(b * NH + hh) * NN + n0 + nn) * 64 + hf * 32;
            #pragma unroll
            for (int i = 0; i < 4; ++i) *(half8*)(dst + i * 8) = hv[i];
        } else {
            // stage [cl 128][n 64] pitch 72, row-write per cout
            __syncthreads();
            #pragma unroll
            for (int rt = 0; rt < 2; ++rt)
                #pragma unroll
                for (int nt = 0; nt < 4; ++nt)
                    #pragma unroll
                    for (int r = 0; r < 4; ++r)
                        Es[(w * 32 + rt * 16 + q * 4 + r) * 72 + nt * 16 + c] =
                            (_Float16)(acc[rt][nt][r] +
                                       bias[cout0 + w * 32 + rt * 16 + q * 4 + r]);
            __syncthreads();
            const int cl = t >> 1, noff = (t & 1) * 32;
            const int cout = cout0 + cl;
            const int hh = cout & 3, dd = cout >> 2;
            _Float16* dst = Yv + ((size_t)(b * NH + hh) * 64 + dd) * NN + n0 + noff;
            #pragma unroll
            for (int i = 0; i < 4; ++i)
                *(half8*)(dst + i * 8) = *(const half8*)(Es + cl * 72 + noff + i * 8);
        }
    }
}

// ---------------------------------------------------------------------------
// Final projection: packed weights in regs, B-frags DIRECT from PACKED global
// Atp (contiguous 1KB wave-reads). Output fp32 [b][cout][n].
// grid (32, 8, 2): z = cout half.
// ---------------------------------------------------------------------------
__global__ __launch_bounds__(256, 3) void conv_o(
    const _Float16* __restrict__ Wf, const float* __restrict__ bias,
    const _Float16* __restrict__ At, float* __restrict__ out)
{
    const int n0 = blockIdx.x * 64;
    const int b  = blockIdx.y;
    const int hf = blockIdx.z;
    const int cout0 = hf * 128;

    const int t = threadIdx.x;
    const int w = t >> 6, l = t & 63, c = l & 15, q = l >> 4;

    __shared__ float fs[128 * 66];   // 33.8 KB

    // packed af: cb = hf*8 + w*2 + rt
    half8 af[2][8];
    {
        const _Float16* wp = Wf + (size_t)(hf * 8 + w * 2) * 4096 + l * 8;
        #pragma unroll
        for (int rt = 0; rt < 2; ++rt)
            #pragma unroll
            for (int ch = 0; ch < 8; ++ch)
                af[rt][ch] = *(const half8*)(wp + rt * 4096 + ch * 512);
    }

    floatx4 acc[2][4];
    #pragma unroll
    for (int rt = 0; rt < 2; ++rt)
        #pragma unroll
        for (int nt = 0; nt < 4; ++nt) acc[rt][nt] = (floatx4){0.f, 0.f, 0.f, 0.f};

    #pragma unroll
    for (int ch = 0; ch < 8; ++ch)
        #pragma unroll
        for (int nt = 0; nt < 4; ++nt) {
            half8 bx = *(const half8*)(At +
                ((((size_t)b * 128 + (n0 >> 4) + nt) * 8 + ch) << 9) + l * 8);
            acc[0][nt] = MFMA32(af[0][ch], bx, acc[0][nt]);
            acc[1][nt] = MFMA32(af[1][ch], bx, acc[1][nt]);
        }

    #pragma unroll
    for (int rt = 0; rt < 2; ++rt)
        #pragma unroll
        for (int nt = 0; nt < 4; ++nt)
            #pragma unroll
            for (int r = 0; r < 4; ++r)
                fs[(w * 32 + rt * 16 + q * 4 + r) * 66 + nt * 16 + c] =
                    acc[rt][nt][r] + bias[cout0 + w * 32 + rt * 16 + q * 4 + r];
    __syncthreads();
    const int cl = t >> 1, noff = (t & 1) * 32;
    float* dst = out + (size_t)b * DD * NN + (size_t)(cout0 + cl) * NN + n0 + noff;
    #pragma unroll
    for (int i = 0; i < 8; ++i)
        *(float4*)(dst + i * 4) = *(const float4*)(fs + cl * 66 + noff + i * 4);
}

// ---------------------------------------------------------------------------
// MFMA flash attention v13 = v11 (round-8 best: in-block m-split, 8 waves,
// m-tile 64, K+V dbuf LDS, jj=2, packed p8, lp via ones-MFMA, setprio(1),
// packed-At epilogue) with the main-loop __syncthreads() replaced by
// { s_waitcnt lgkmcnt(0); raw s_barrier } (minimal T4): __syncthreads emits
// vmcnt(0) before s_barrier, draining the 8 K/V prefetch loads (HBM ~900cy >
// compute ~500cy) into all 16 barriers. Raw barrier orders only the LDS
// writes; prefetches stay in flight, consumed by next iter's STAGE8 under
// the compiler's own vmcnt guard. Epilogue keeps full __syncthreads().
// grid (16, 4, 8) = 512 blocks = 2 blocks/CU.
// ---------------------------------------------------------------------------
__global__ __launch_bounds__(512, 4) void attn_mfma13(
    const _Float16* __restrict__ Qt, const _Float16* __restrict__ Kt,
    const _Float16* __restrict__ V, _Float16* __restrict__ At)
{
    const int n0 = blockIdx.x * 128;
    const int h  = blockIdx.y;
    const int b  = blockIdx.z;
    const int t  = threadIdx.x;
    const int w  = t >> 6, l = t & 63, c = l & 15, q = l >> 4;
    const int mh = w >> 2;          // m-half (0: m<1024, 1: m>=1024)
    const int w4 = w & 3;           // wave-in-half -> q-col group
    const int tp = t & 255;         // thread-in-half

    const size_t bh = (size_t)(b * NH + h);

    // layout: [mh][buf][Ks 4608 | Vs 4608] = 2*2*9216 = 36864 halfs (73.7 KB)
    __shared__ _Float16 smem[36864];
    _Float16* base = smem + mh * 18432;

    // Q frags: wave covers q-cols w4*32 + jj*16 + c
    half8 bq2[2][2];
    #pragma unroll
    for (int jj = 0; jj < 2; ++jj)
        #pragma unroll
        for (int ch = 0; ch < 2; ++ch)
            bq2[jj][ch] = *(const half8*)(Qt +
                (bh * NN + n0 + w4 * 32 + jj * 16 + c) * 64 + ch * 32 + q * 8);

    // all-ones A-frag for the lp row-sum MFMA
    half8 ones;
    #pragma unroll
    for (int i = 0; i < 8; ++i) ones[i] = (_Float16)1.0f;

    floatx4 lpa[2];
    floatx4 o[2][4];
    #pragma unroll
    for (int jj = 0; jj < 2; ++jj) {
        lpa[jj] = (floatx4){0.f, 0.f, 0.f, 0.f};
        #pragma unroll
        for (int dt = 0; dt < 4; ++dt) o[jj][dt] = (floatx4){0.f, 0.f, 0.f, 0.f};
    }

    // staging (256 thr per half): K row 64x64 by 4 thr; V d-row 64x64m by 4 thr
    const int ksr = tp >> 2, ksc = (tp & 3) * 16;
    const int vr  = tp >> 2, vcb = (tp & 3) * 16;
    const _Float16* Kg = Kt + bh * NN * 64 + (size_t)mh * 1024 * 64;  // [m][d]
    const _Float16* Vg = V + bh * 64 * NN + mh * 1024;                // [d][n]

    half8 kpre[2], vpre[2];
    #pragma unroll
    for (int u = 0; u < 2; ++u) {
        kpre[u] = *(const half8*)(Kg + (size_t)ksr * 64 + ksc + u * 8);
        vpre[u] = *(const half8*)(Vg + (size_t)vr * NN + vcb + u * 8);
    }

#define STAGE8(BUFP)                                                            \
    {                                                                           \
        _Float16* Ksp_ = (BUFP);                                                \
        *(half8*)(Ksp_ + ksr * 72 + ksc)     = kpre[0];                         \
        *(half8*)(Ksp_ + ksr * 72 + ksc + 8) = kpre[1];                         \
        _Float16* Vsp_ = (BUFP) + 4608;                                         \
        _Pragma("unroll")                                                       \
        for (int u = 0; u < 2; ++u) {                                           \
            const int mb = vcb + u * 8;                                         \
            const int p0 = (mb & ~31) + (((mb >> 2) & 3) << 3) +                \
                           (((mb >> 4) & 1) << 2);                              \
            half4_t lo, hi;                                                     \
            _Pragma("unroll")                                                   \
            for (int j = 0; j < 4; ++j) { lo[j] = vpre[u][j]; hi[j] = vpre[u][4 + j]; } \
            *(half4_t*)(Vsp_ + vr * 72 + p0)     = lo;                          \
            *(half4_t*)(Vsp_ + vr * 72 + p0 + 8) = hi;                          \
        }                                                                       \
    }

    // prologue: stage tile0 -> buf0, prefetch tile1
    STAGE8(base);
    #pragma unroll
    for (int u = 0; u < 2; ++u) {
        kpre[u] = *(const half8*)(Kg + (size_t)(64 + ksr) * 64 + ksc + u * 8);
        vpre[u] = *(const half8*)(Vg + (size_t)vr * NN + 64 + vcb + u * 8);
    }
    asm volatile("s_waitcnt lgkmcnt(0)" ::: "memory");
    __builtin_amdgcn_s_barrier();

    for (int it = 0; it < 16; ++it) {
        if (it < 15) STAGE8(base + ((it + 1) & 1) * 9216);
        {
            const int mn = (it + 2 < 16) ? (it + 2) * 64 : it * 64;
            #pragma unroll
            for (int u = 0; u < 2; ++u) {
                kpre[u] = *(const half8*)(Kg + (size_t)(mn + ksr) * 64 + ksc + u * 8);
                vpre[u] = *(const half8*)(Vg + (size_t)vr * NN + mn + vcb + u * 8);
            }
        }
        const _Float16* Ks = base + (it & 1) * 9216;
        const _Float16* Vs = Ks + 4608;
        __builtin_amdgcn_s_setprio(1);
        #pragma unroll
        for (int mt2 = 0; mt2 < 2; ++mt2) {
            uint32x4 pu[2];
            #pragma unroll
            for (int hfm = 0; hfm < 2; ++hfm) {
                const int mt = mt2 * 2 + hfm;
                half8 ak0 = *(const half8*)(Ks + (mt * 16 + c) * 72 + q * 8);
                half8 ak1 = *(const half8*)(Ks + (mt * 16 + c) * 72 + 32 + q * 8);
                #pragma unroll
                for (int jj = 0; jj < 2; ++jj) {
                    floatx4 s = {0.f, 0.f, 0.f, 0.f};
                    s = MFMA32(ak0, bq2[jj][0], s);
                    s = MFMA32(ak1, bq2[jj][1], s);
                    float e0 = exp2f(s[0]), e1 = exp2f(s[1]);
                    float e2 = exp2f(s[2]), e3 = exp2f(s[3]);
                    pu[jj][hfm * 2 + 0] = __builtin_bit_cast(unsigned int,
                        __builtin_amdgcn_cvt_pkrtz(e0, e1));
                    pu[jj][hfm * 2 + 1] = __builtin_bit_cast(unsigned int,
                        __builtin_amdgcn_cvt_pkrtz(e2, e3));
                }
            }
            const half8 p80 = __builtin_bit_cast(half8, pu[0]);
            const half8 p81 = __builtin_bit_cast(half8, pu[1]);
            lpa[0] = MFMA32(ones, p80, lpa[0]);
            lpa[1] = MFMA32(ones, p81, lpa[1]);
            #pragma unroll
            for (int dt = 0; dt < 4; ++dt) {
                half8 av = *(const half8*)(Vs + (dt * 16 + c) * 72 + mt2 * 32 + q * 8);
                o[0][dt] = MFMA32(av, p80, o[0][dt]);
                o[1][dt] = MFMA32(av, p81, o[1][dt]);
            }
        }
        __builtin_amdgcn_s_setprio(0);
        // T4-lite barrier: order LDS ops only; leave VMEM prefetches in flight
        asm volatile("s_waitcnt lgkmcnt(0)" ::: "memory");
        __builtin_amdgcn_s_barrier();
    }
#undef STAGE8

    // lpa[jj][r] identical over r (ones-MFMA rows): lane's q-col sum is lpa[jj][0]

    // merge halves via LDS: fo f32 [col 128][68], lq f32 [col 128],
    // fsm f16 [col 128][72] at disjoint offsets (54 KB total <= 73.7 KB)
    float* fo = (float*)smem;                    // 34816 B
    float* lq = (float*)smem + 128 * 68;         // 512 B
    _Float16* fsm = (_Float16*)(lq + 128);       // 18432 B

    if (mh == 1) {
        #pragma unroll
        for (int jj = 0; jj < 2; ++jj) {
            const int col = w4 * 32 + jj * 16 + c;
            #pragma unroll
            for (int dt = 0; dt < 4; ++dt)
                #pragma unroll
                for (int r = 0; r < 4; ++r)
                    fo[col * 68 + dt * 16 + q * 4 + r] = o[jj][dt][r];
        }
        if (l < 16) {
            lq[w4 * 32 + c]      = lpa[0][0];
            lq[w4 * 32 + 16 + c] = lpa[1][0];
        }
    }
    __syncthreads();
    if (mh == 0) {
        #pragma unroll
        for (int jj = 0; jj < 2; ++jj) {
            const int col = w4 * 32 + jj * 16 + c;
            const float lpt = lpa[jj][0] + lq[col];
            const float inv = 1.f / lpt;
            #pragma unroll
            for (int dt = 0; dt < 4; ++dt) {
                half4_t hv;
                #pragma unroll
                for (int r = 0; r < 4; ++r)
                    hv[r] = (_Float16)((o[jj][dt][r] +
                                        fo[col * 68 + dt * 16 + q * 4 + r]) * inv);
                *(half4_t*)(fsm + col * 72 + dt * 16 + q * 4) = hv;
            }
        }
    }
    __syncthreads();
    if (t < 256) {
        const int seg = (t & 3) * 16;
        const int ch = h * 2 + (seg >> 5);
        const int q0 = (seg >> 3) & 3;
        #pragma unroll
        for (int rr = 0; rr < 2; ++rr) {
            const int rn = rr * 64 + (t >> 2);
            const int n = n0 + rn;
            _Float16* dst = At + ((((size_t)b * 128 + (n >> 4)) * 8 + ch) << 9)
                            + ((n & 15) + 16 * q0) * 8;
            *(half8*)(dst)       = *(const half8*)(fsm + rn * 72 + seg);
            *(half8*)(dst + 128) = *(const half8*)(fsm + rn * 72 + seg + 8);
        }
    }
}

extern "C" void kernel_launch(void* const* d_in, const int* in_sizes, int n_in,
                              void* d_out, int out_size, void* d_ws, size_t ws_size,
                              hipStream_t stream) {
    const float* query = (const float*)d_in[0];
    const float* key_  = (const float*)d_in[1];
    const float* value = (const float*)d_in[2];
    const float* wq    = (const float*)d_in[3];
    const float* bq    = (const float*)d_in[4];
    const float* wk    = (const float*)d_in[5];
    const float* bk    = (const float*)d_in[6];
    const float* wv    = (const float*)d_in[7];
    const float* bv    = (const float*)d_in[8];
    const float* wm    = (const float*)d_in[9];
    const float* bm    = (const float*)d_in[10];
    float* out = (float*)d_out;

    _Float16* ws = (_Float16*)d_ws;
    _Float16* wqf = ws;
    _Float16* wkf = wqf + 65536;
    _Float16* wvf = wkf + 65536;
    _Float16* wmf = wvf + 65536;
    const size_t e16 = (size_t)BB * NH * NN * DH;   // 4,194,304
    _Float16* qf = ws + 262144;
    _Float16* kf = qf + e16;
    _Float16* vf = kf + e16;
    _Float16* at = vf + e16;

    prep_weights<<<256, 256, 0, stream>>>(wq, wk, wv, wm, wqf, wkf, wvf, wmf);
    conv_qkv<<<dim3(32, 8, 3), 256, 0, stream>>>(wqf, wkf, wvf, bq, bk, bv,
                                                 query, key_, value, qf, kf, vf);
    attn_mfma13<<<dim3(16, 4, 8), 512, 0, stream>>>(qf, kf, vf, at);
    conv_o<<<dim3(32, 8, 2), 256, 0, stream>>>(wmf, bm, at, out);
}